// Round 21
// baseline (2918.910 us; speedup 1.0000x reference)
//
#include <hip/hip_runtime.h>

// MemoryBlock: B=4,S=1024,H=1024,M=32768,NH=1.  rows R=B*S=4096, D=1024, M=32768
#define SCALE 0.03125f  // 1/sqrt(1024) exact
#define BAND_EPS 1e-6
#define BAND_CAP 8192
#define RB 4            // band slots per repair block
#define NCHUNK 8        // row chunks (4096/512) for repair parallelism

typedef unsigned int u32;
typedef unsigned short u16;
typedef unsigned long long u64;
typedef __attribute__((ext_vector_type(8))) short bf16x8;
typedef __attribute__((ext_vector_type(4))) float f32x4;

#define MFMA16(A,B,C) __builtin_amdgcn_mfma_f32_16x16x32_bf16(A,B,C,0,0,0)

__device__ __forceinline__ u32 fenc(float x){ u32 u=__float_as_uint(x); return (u&0x80000000u)? ~u : (u|0x80000000u); }
__device__ __forceinline__ float fdec(u32 e){ return (e&0x80000000u)? __uint_as_float(e&0x7FFFFFFFu) : __uint_as_float(~e); }
__device__ __forceinline__ u16 f2bf(float f){ u32 u=__float_as_uint(f); u32 r=(u + 0x7FFFu + ((u>>16)&1u))>>16; return (u16)r; }
__device__ __forceinline__ float bf2f(u16 h){ return __uint_as_float(((u32)h)<<16); }

// Q projection in f64 -> Qhi f32; optionally bf16 hi (and lo if Ql != null)
__global__ __launch_bounds__(256) void k_projq64(const float* __restrict__ X, const float* __restrict__ W,
    const float* __restrict__ bias, float* __restrict__ Qhi, u16* __restrict__ Qh, u16* __restrict__ Ql)
{
  __shared__ float Xs[16][68], Ws[16][68];
  int t=threadIdx.x, ty=t>>4, tx=t&15;
  int row0=blockIdx.y*64, col0=blockIdx.x*64;
  int lr=t>>2, lk=(t&3)*4;
  double acc[4][4]={};
  for (int k0=0;k0<1024;k0+=16){
    __syncthreads();
    {
      float4 x = *(const float4*)(X + (size_t)(row0+lr)*1024 + k0 + lk);
      float4 w = *(const float4*)(W + (size_t)(col0+lr)*1024 + k0 + lk);
      Xs[lk+0][lr]=x.x; Xs[lk+1][lr]=x.y; Xs[lk+2][lr]=x.z; Xs[lk+3][lr]=x.w;
      Ws[lk+0][lr]=w.x; Ws[lk+1][lr]=w.y; Ws[lk+2][lr]=w.z; Ws[lk+3][lr]=w.w;
    }
    __syncthreads();
    #pragma unroll
    for (int kk=0;kk<16;kk++){
      double a[4], b[4];
      #pragma unroll
      for (int i=0;i<4;i++) a[i] = (double)Xs[kk][ty*4+i];
      #pragma unroll
      for (int j=0;j<4;j++) b[j] = (double)Ws[kk][tx*4+j];
      #pragma unroll
      for (int i=0;i<4;i++)
        #pragma unroll
        for (int j=0;j<4;j++)
          acc[i][j] = fma(a[i], b[j], acc[i][j]);
    }
  }
  #pragma unroll
  for (int i=0;i<4;i++)
    #pragma unroll
    for (int j=0;j<4;j++){
      double q = acc[i][j] + (double)bias[col0+tx*4+j];
      float hi = (float)q;
      size_t off = (size_t)(row0+ty*4+i)*1024 + col0 + tx*4 + j;
      Qhi[off] = hi;
      if (Qh){
        u16 h = f2bf(hi);
        Qh[off] = h;
        if (Ql) Ql[off] = f2bf(hi - bf2f(h));
      }
    }
}

// single-row projection (f64): k[0,-1], v[0,-1] (hs flat row 1023)
__global__ __launch_bounds__(256) void k_rowproj(const float* __restrict__ hs,
    const float* __restrict__ Wk, const float* __restrict__ bk,
    const float* __restrict__ Wv, const float* __restrict__ bv,
    float* __restrict__ krow, float* __restrict__ vrow)
{
  int b = blockIdx.x; int which = b >> 10; int o = b & 1023; int t = threadIdx.x;
  const float* W = which ? Wv : Wk;
  const float* bias = which ? bv : bk;
  const float* x = hs + (size_t)1023*1024;
  double s = 0;
  for (int k=t;k<1024;k+=256) s += (double)x[k] * (double)W[(size_t)o*1024+k];
  __shared__ double sd[256];
  sd[t]=s; __syncthreads();
  for (int off=128;off>0;off>>=1){ if(t<off) sd[t]+=sd[t+off]; __syncthreads(); }
  if (t==0){ float* dst = which? vrow : krow; dst[o] = (float)(sd[0] + (double)bias[o]); }
}

// f32 -> bf16 bulk convert (16 elems/thread)
__global__ __launch_bounds__(256) void k_cvt_mk(const float* __restrict__ src, u16* __restrict__ dst)
{
  size_t base = ((size_t)blockIdx.x*256 + threadIdx.x) * 16;
  float v[16];
  #pragma unroll
  for (int q=0;q<4;q++) *(float4*)&v[q*4] = *(const float4*)(src + base + q*4);
  u16 h[16];
  #pragma unroll
  for (int q=0;q<16;q++) h[q] = f2bf(v[q]);
  *(uint4*)(dst+base)   = *(uint4*)&h[0];
  *(uint4*)(dst+base+8) = *(uint4*)&h[8];
}

// MV -> MVT[mpair][d] u32 = bf16(MV[2mp][d]) | bf16(MV[2mp+1][d])<<16
__global__ __launch_bounds__(256) void k_cvt_mvt(const float* __restrict__ MV, u32* __restrict__ MVT)
{
  size_t mp = blockIdx.x; int d = threadIdx.x*4;
  float4 r0 = *(const float4*)(MV + (2*mp  )*1024 + d);
  float4 r1 = *(const float4*)(MV + (2*mp+1)*1024 + d);
  u32 o[4];
  o[0] = (u32)f2bf(r0.x) | ((u32)f2bf(r1.x)<<16);
  o[1] = (u32)f2bf(r0.y) | ((u32)f2bf(r1.y)<<16);
  o[2] = (u32)f2bf(r0.z) | ((u32)f2bf(r1.z)<<16);
  o[3] = (u32)f2bf(r0.w) | ((u32)f2bf(r1.w)<<16);
  *(uint4*)(MVT + mp*1024 + d) = *(uint4*)o;
}

// ---------- MFMA core, in-loop f32->bf16 conversion (fallback path) ----------
template<bool SPLIT>
__device__ __forceinline__ void sweep_core(
    const float* __restrict__ Qg, const float* __restrict__ MKg,
    int row0, int col0,
    u16 (*Ah)[40], u16 (*Al)[40], u16 (*Bh)[40],
    f32x4 acc[2][8])
{
  int t = threadIdx.x;
  int w = t >> 6, g = (t >> 4) & 3, c = t & 15;
  int srow = t >> 1, sq = (t & 1) * 16;
  const float* xg = Qg  + (size_t)(row0 + srow)*1024 + sq;
  const float* wg = MKg + (size_t)(col0 + srow)*1024 + sq;
  float xr[16], wr[16];
  #pragma unroll
  for (int q=0;q<4;q++){
    *(float4*)&xr[q*4] = *(const float4*)(xg + q*4);
    *(float4*)&wr[q*4] = *(const float4*)(wg + q*4);
  }
  for (int k0 = 0; k0 < 1024; k0 += 32){
    u16 ah[16], al[16], bh[16];
    #pragma unroll
    for (int q=0;q<16;q++){
      u16 h = f2bf(xr[q]); ah[q]=h;
      bh[q] = f2bf(wr[q]);
      if constexpr (SPLIT) al[q]=f2bf(xr[q]-bf2f(h));
    }
    __syncthreads();
    *(uint4*)&Ah[srow][sq]   = *(uint4*)&ah[0];
    *(uint4*)&Ah[srow][sq+8] = *(uint4*)&ah[8];
    *(uint4*)&Bh[srow][sq]   = *(uint4*)&bh[0];
    *(uint4*)&Bh[srow][sq+8] = *(uint4*)&bh[8];
    if constexpr (SPLIT){
      *(uint4*)&Al[srow][sq]   = *(uint4*)&al[0];
      *(uint4*)&Al[srow][sq+8] = *(uint4*)&al[8];
    }
    __syncthreads();
    if (k0 + 32 < 1024){
      #pragma unroll
      for (int q=0;q<4;q++){
        *(float4*)&xr[q*4] = *(const float4*)(xg + k0+32 + q*4);
        *(float4*)&wr[q*4] = *(const float4*)(wg + k0+32 + q*4);
      }
    }
    bf16x8 afh[2], afl[2];
    #pragma unroll
    for (int fi=0; fi<2; fi++){
      afh[fi] = *(const bf16x8*)&Ah[w*32 + fi*16 + c][g*8];
      if constexpr (SPLIT) afl[fi] = *(const bf16x8*)&Al[w*32 + fi*16 + c][g*8];
    }
    #pragma unroll
    for (int fj=0; fj<8; fj++){
      bf16x8 bfh = *(const bf16x8*)&Bh[fj*16 + c][g*8];
      #pragma unroll
      for (int fi=0; fi<2; fi++){
        acc[fi][fj] = MFMA16(afh[fi], bfh, acc[fi][fj]);
        if constexpr (SPLIT)
          acc[fi][fj] = MFMA16(afl[fi], bfh, acc[fi][fj]);
      }
    }
  }
}

// ---------- MFMA core, pre-converted bf16, 256-row tile (fast path) ----------
// acc[4][8]; one thread stages one A-row (4x uint4), two threads per B-row.
// 12 b128 LDS reads feed 32 MFMA per K-step (amortized B-gather, pvmp-proven).
__device__ __forceinline__ void sweep_core_pre256(
    const u16* __restrict__ Ag, const u16* __restrict__ Bg,
    int row0, int col0,
    u16 (*Ah)[40], u16 (*Bh)[40],
    f32x4 acc[4][8])
{
  int t = threadIdx.x;
  int w = t >> 6, g = (t >> 4) & 3, c = t & 15;
  int bsrow = t >> 1, bsq = (t & 1) * 16;
  const u16* xa = Ag + (size_t)(row0 + t)*1024;
  const u16* wb = Bg + (size_t)(col0 + bsrow)*1024 + bsq;
  uint4 a0=*(const uint4*)xa,      a1=*(const uint4*)(xa+8);
  uint4 a2=*(const uint4*)(xa+16), a3=*(const uint4*)(xa+24);
  uint4 b0=*(const uint4*)wb,      b1=*(const uint4*)(wb+8);
  for (int k0 = 0; k0 < 1024; k0 += 32){
    __syncthreads();
    *(uint4*)&Ah[t][0]  = a0;
    *(uint4*)&Ah[t][8]  = a1;
    *(uint4*)&Ah[t][16] = a2;
    *(uint4*)&Ah[t][24] = a3;
    *(uint4*)&Bh[bsrow][bsq]   = b0;
    *(uint4*)&Bh[bsrow][bsq+8] = b1;
    __syncthreads();
    if (k0 + 32 < 1024){
      a0=*(const uint4*)(xa+k0+32); a1=*(const uint4*)(xa+k0+40);
      a2=*(const uint4*)(xa+k0+48); a3=*(const uint4*)(xa+k0+56);
      b0=*(const uint4*)(wb+k0+32); b1=*(const uint4*)(wb+k0+40);
    }
    bf16x8 af[4];
    af[0] = *(const bf16x8*)&Ah[w*64      + c][g*8];
    af[1] = *(const bf16x8*)&Ah[w*64 + 16 + c][g*8];
    af[2] = *(const bf16x8*)&Ah[w*64 + 32 + c][g*8];
    af[3] = *(const bf16x8*)&Ah[w*64 + 48 + c][g*8];
    #pragma unroll
    for (int fj=0; fj<8; fj++){
      bf16x8 bfh = *(const bf16x8*)&Bh[fj*16 + c][g*8];
      acc[0][fj] = MFMA16(af[0], bfh, acc[0][fj]);
      acc[1][fj] = MFMA16(af[1], bfh, acc[1][fj]);
      acc[2][fj] = MFMA16(af[2], bfh, acc[2][fj]);
      acc[3][fj] = MFMA16(af[3], bfh, acc[3][fj]);
    }
  }
}

// sweep1 epilogue (fallback, 128-tile): rowmax + Z
__device__ __forceinline__ void sweep1_epi(f32x4 acc[2][8], int row0,
    double* Zrow, u32* rmk)
{
  int t=threadIdx.x, w=t>>6, g=(t>>4)&3, c=t&15;
  #pragma unroll
  for (int fi=0;fi<2;fi++){
    #pragma unroll
    for (int r=0;r<4;r++){
      float mx=-1e30f, sm=0.f;
      #pragma unroll
      for (int fj=0;fj<8;fj++){
        float sc = acc[fi][fj][r]*SCALE;
        mx = fmaxf(mx, sc);
        sm += expf(sc);
      }
      #pragma unroll
      for (int o=1;o<16;o<<=1){
        mx = fmaxf(mx, __shfl_xor(mx,o,64));
        sm += __shfl_xor(sm,o,64);
      }
      if (c==0){
        int row = row0 + w*32 + fi*16 + g*4 + r;
        atomicMax(&rmk[row], fenc(mx));
        atomicAdd(&Zrow[row], (double)sm);
      }
    }
  }
}

__global__ __launch_bounds__(256) void k_sweep1m(const float* __restrict__ Q,
    const float* __restrict__ MK, double* __restrict__ Zrow, u32* __restrict__ rmk)
{
  __shared__ __align__(16) u16 ldsbuf[2*128*40];
  u16 (*Ah)[40]=(u16(*)[40])(ldsbuf);
  u16 (*Bh)[40]=(u16(*)[40])(ldsbuf+128*40);
  int row0=blockIdx.y*128, col0=blockIdx.x*128;
  f32x4 acc[2][8];
  #pragma unroll
  for (int fi=0;fi<2;fi++)
    #pragma unroll
    for (int fj=0;fj<8;fj++) acc[fi][fj] = (f32x4){0.f,0.f,0.f,0.f};
  sweep_core<false>(Q, MK, row0, col0, Ah, Ah, Bh, acc);
  sweep1_epi(acc, row0, Zrow, rmk);
}

// fast sweep1: 256-row tile, 1-pass bf16
__global__ __launch_bounds__(256) void k_sweep1p(const u16* __restrict__ Qh,
    const u16* __restrict__ MKh, double* __restrict__ Zrow, u32* __restrict__ rmk)
{
  __shared__ __align__(16) u16 Ah[256][40];   // 20 KB
  __shared__ __align__(16) u16 Bh[128][40];   // 10 KB
  int t=threadIdx.x, w=t>>6, g=(t>>4)&3, c=t&15;
  int row0=blockIdx.y*256, col0=blockIdx.x*128;
  f32x4 acc[4][8];
  #pragma unroll
  for (int fi=0;fi<4;fi++)
    #pragma unroll
    for (int fj=0;fj<8;fj++) acc[fi][fj] = (f32x4){0.f,0.f,0.f,0.f};
  sweep_core_pre256(Qh, MKh, row0, col0, Ah, Bh, acc);
  #pragma unroll
  for (int fi=0;fi<4;fi++){
    #pragma unroll
    for (int r=0;r<4;r++){
      float mx=-1e30f, sm=0.f;
      #pragma unroll
      for (int fj=0;fj<8;fj++){
        float sc = acc[fi][fj][r]*SCALE;
        mx = fmaxf(mx, sc);
        sm += expf(sc);
      }
      #pragma unroll
      for (int o=1;o<16;o<<=1){
        mx = fmaxf(mx, __shfl_xor(mx,o,64));
        sm += __shfl_xor(sm,o,64);
      }
      if (c==0){
        int row = row0 + w*64 + fi*16 + g*4 + r;
        atomicMax(&rmk[row], fenc(mx));
        atomicAdd(&Zrow[row], (double)sm);
      }
    }
  }
}

__global__ __launch_bounds__(256) void k_invz(const double* __restrict__ Z, const u32* __restrict__ rmk,
    float* __restrict__ invZ, double* __restrict__ invZd, float* __restrict__ rowmax)
{
  int r = blockIdx.x*256 + threadIdx.x;
  double iz = 1.0 / Z[r];
  invZ[r] = (float)iz;
  invZd[r] = iz;
  rowmax[r] = fdec(rmk[r]);
}

// sweep2 epilogue (fallback, 128-tile): p, NT P store, f64 col-sums, counts
__device__ __forceinline__ void sweep2_epi(f32x4 acc[2][8], int row0, int col0,
    const float* invZ, double* imp, int* cnt, u16* P, u16* ldsbuf)
{
  int t=threadIdx.x, w=t>>6, g=(t>>4)&3, c=t&15;
  double colp[8]={0,0,0,0,0,0,0,0};
  int    colc[8]={0,0,0,0,0,0,0,0};
  #pragma unroll
  for (int fi=0;fi<2;fi++){
    float iz[4];
    #pragma unroll
    for (int r=0;r<4;r++) iz[r] = invZ[row0 + w*32 + fi*16 + g*4 + r];
    #pragma unroll
    for (int fj=0;fj<8;fj++){
      #pragma unroll
      for (int r=0;r<4;r++){
        float p = expf(acc[fi][fj][r]*SCALE)*iz[r];
        int row = row0 + w*32 + fi*16 + g*4 + r;
        __builtin_nontemporal_store(f2bf(p), &P[(size_t)row*32768 + col0 + fj*16 + c]);
        colp[fj] += (double)p;
        colc[fj] += (p > 0.01f) ? 1 : 0;
      }
    }
  }
  __syncthreads();
  double (*red)[128] = (double(*)[128])ldsbuf;
  #pragma unroll
  for (int fj=0;fj<8;fj++) red[w*4+g][fj*16+c] = colp[fj];
  __syncthreads();
  if (t < 128){
    double s=0;
    #pragma unroll
    for (int q=0;q<16;q++) s += red[q][t];
    atomicAdd(&imp[col0+t], s);
  }
  __syncthreads();
  #pragma unroll
  for (int fj=0;fj<8;fj++) red[w*4+g][fj*16+c] = (double)colc[fj];
  __syncthreads();
  if (t < 128){
    double s=0;
    #pragma unroll
    for (int q=0;q<16;q++) s += red[q][t];
    int ci = (int)(s+0.5);
    if (ci) atomicAdd(&cnt[col0+t], ci);
  }
}

__global__ __launch_bounds__(256) void k_sweep2m(const float* __restrict__ Q,
    const float* __restrict__ MK, const float* __restrict__ invZ,
    double* __restrict__ imp, int* __restrict__ cnt, u16* __restrict__ P)
{
  __shared__ __align__(16) u16 ldsbuf[3*128*40];
  u16 (*Ah)[40]=(u16(*)[40])(ldsbuf);
  u16 (*Al)[40]=(u16(*)[40])(ldsbuf+128*40);
  u16 (*Bh)[40]=(u16(*)[40])(ldsbuf+2*128*40);
  int row0=blockIdx.y*128, col0=blockIdx.x*128;
  f32x4 acc[2][8];
  #pragma unroll
  for (int fi=0;fi<2;fi++)
    #pragma unroll
    for (int fj=0;fj<8;fj++) acc[fi][fj] = (f32x4){0.f,0.f,0.f,0.f};
  sweep_core<true>(Q, MK, row0, col0, Ah, Al, Bh, acc);
  sweep2_epi(acc, row0, col0, invZ, imp, cnt, P, ldsbuf);
}

// fast sweep2: 256-row tile, 1-pass bf16; band repair fixes boundary slots in f64.
__global__ __launch_bounds__(256) void k_sweep2p(const u16* __restrict__ Qh,
    const u16* __restrict__ MKh, const float* __restrict__ invZ,
    double* __restrict__ imp, int* __restrict__ cnt, u16* __restrict__ P)
{
  __shared__ __align__(16) u16 Ah[256][40];   // 20 KB (red aliases: 16KB needed)
  __shared__ __align__(16) u16 Bh[128][40];   // 10 KB
  int t=threadIdx.x, w=t>>6, g=(t>>4)&3, c=t&15;
  int row0=blockIdx.y*256, col0=blockIdx.x*128;
  f32x4 acc[4][8];
  #pragma unroll
  for (int fi=0;fi<4;fi++)
    #pragma unroll
    for (int fj=0;fj<8;fj++) acc[fi][fj] = (f32x4){0.f,0.f,0.f,0.f};
  sweep_core_pre256(Qh, MKh, row0, col0, Ah, Bh, acc);

  double colp[8]={0,0,0,0,0,0,0,0};
  int    colc[8]={0,0,0,0,0,0,0,0};
  #pragma unroll
  for (int fi=0;fi<4;fi++){
    float iz[4];
    #pragma unroll
    for (int r=0;r<4;r++) iz[r] = invZ[row0 + w*64 + fi*16 + g*4 + r];
    #pragma unroll
    for (int fj=0;fj<8;fj++){
      #pragma unroll
      for (int r=0;r<4;r++){
        float p = expf(acc[fi][fj][r]*SCALE)*iz[r];
        int row = row0 + w*64 + fi*16 + g*4 + r;
        __builtin_nontemporal_store(f2bf(p), &P[(size_t)row*32768 + col0 + fj*16 + c]);
        colp[fj] += (double)p;
        colc[fj] += (p > 0.01f) ? 1 : 0;
      }
    }
  }
  __syncthreads();
  double (*red)[128] = (double(*)[128])&Ah[0][0];
  #pragma unroll
  for (int fj=0;fj<8;fj++) red[w*4+g][fj*16+c] = colp[fj];
  __syncthreads();
  if (t < 128){
    double s=0;
    #pragma unroll
    for (int q=0;q<16;q++) s += red[q][t];
    atomicAdd(&imp[col0+t], s);
  }
  __syncthreads();
  #pragma unroll
  for (int fj=0;fj<8;fj++) red[w*4+g][fj*16+c] = (double)colc[fj];
  __syncthreads();
  if (t < 128){
    double s=0;
    #pragma unroll
    for (int q=0;q<16;q++) s += red[q][t];
    int ci = (int)(s+0.5);
    if (ci) atomicAdd(&cnt[col0+t], ci);
  }
}

// ---------------- single-block radix select on f32 vals ---------------------
template<int MODE>
__global__ __launch_bounds__(1024) void k_select(const double* __restrict__ imp,
    const float* __restrict__ mage, double* __restrict__ vsout, int* __restrict__ sel)
{
  __shared__ int hist[256];
  __shared__ int scanbuf[1024];
  __shared__ u32 s_digit; __shared__ int s_rr;
  int t = threadIdx.x;
  int m0 = t*32;
  u32 key[32];
  #pragma unroll
  for (int i=0;i<32;i++){
    int m = m0+i;
    float v = (mage[m] + 1.0f) + (1.0f - (float)imp[m]);
    key[i] = fenc(v);
  }
  u32 prefix = 0, pmask = 0;
  int rr = 1024;
  for (int pass=0; pass<4; pass++){
    int shift = 24 - pass*8;
    if (t<256) hist[t]=0;
    __syncthreads();
    #pragma unroll
    for (int i=0;i<32;i++){
      if ((key[i] & pmask) == prefix)
        atomicAdd(&hist[(key[i]>>shift)&255u], 1);
    }
    __syncthreads();
    if (t==0){
      int cum=0; int d=255;
      for (; d>0; d--){
        if (cum + hist[d] >= rr) break;
        cum += hist[d];
      }
      s_rr = rr - cum;
      s_digit = (u32)d;
    }
    __syncthreads();
    rr = s_rr;
    prefix |= (s_digit << shift);
    pmask  |= (255u << shift);
    __syncthreads();
  }
  u32 keystar = prefix;
  int krem = rr;
  if (MODE==0){
    if (t==0) *vsout = (double)fdec(keystar);
    return;
  }
  int lc = 0;
  #pragma unroll
  for (int i=0;i<32;i++) lc += (key[i]==keystar) ? 1 : 0;
  scanbuf[t] = lc;
  __syncthreads();
  for (int off=1; off<1024; off<<=1){
    int v_ = scanbuf[t];
    int add = (t>=off)? scanbuf[t-off] : 0;
    __syncthreads();
    scanbuf[t] = v_ + add;
    __syncthreads();
  }
  int run = scanbuf[t] - lc;
  #pragma unroll
  for (int i=0;i<32;i++){
    int s_;
    if (key[i] > keystar) s_ = 1;
    else if (key[i] == keystar){ s_ = (run < krem) ? 1 : 0; run++; }
    else s_ = 0;
    sel[m0+i] = s_;
  }
}

__global__ __launch_bounds__(256) void k_band(const double* __restrict__ imp,
    const float* __restrict__ mage, const double* __restrict__ vsp,
    int* __restrict__ bandcnt, int* __restrict__ bandidx)
{
  int m = blockIdx.x*256 + threadIdx.x;
  double v = ((double)mage[m] + 1.0) + (1.0 - imp[m]);
  double vs = *vsp;
  if (fabs(v - vs) <= BAND_EPS){
    int idx = atomicAdd(bandcnt, 1);
    if (idx < BAND_CAP) bandidx[idx] = m;
  }
}

// exact importance for band slots: RB=4 slots x 512-row chunk per block.
__global__ __launch_bounds__(256) void k_repair2(const int* __restrict__ bandcnt, const int* __restrict__ bandidx,
    const float* __restrict__ Qhi, const float* __restrict__ MK,
    const double* __restrict__ invZd, double* __restrict__ partial)
{
  int bc = *bandcnt; if (bc > BAND_CAP) bc = BAND_CAP;
  int s0 = blockIdx.x * RB;
  if (s0 >= bc) return;
  int ns = bc - s0; if (ns > RB) ns = RB;
  int r0 = blockIdx.y * 512;
  __shared__ float mks[RB][1024];   // 16KB
  __shared__ double izl[512];       // 4KB
  __shared__ double red[256];       // 2KB
  int t = threadIdx.x;
  for (int idx = t; idx < RB*1024; idx += 256){
    int j = idx >> 10, d = idx & 1023;
    mks[j][d] = (j < ns) ? MK[(size_t)bandidx[s0+j]*1024 + d] : 0.f;
  }
  for (int r = t; r < 512; r += 256) izl[r] = invZd[r0 + r];
  __syncthreads();
  int wave = t>>6, lane = t&63, d0 = lane*16, sl = lane&3;
  double mkr[RB][16];
  #pragma unroll
  for (int j=0;j<RB;j++)
    #pragma unroll
    for (int q=0;q<16;q++) mkr[j][q] = (double)mks[j][d0+q];
  double acc = 0;
  for (int rr = wave; rr < 512; rr += 4){
    const float4* hp = (const float4*)(Qhi + (size_t)(r0+rr)*1024 + d0);
    float4 h0=hp[0], h1=hp[1], h2=hp[2], h3=hp[3];
    double hh[16]={h0.x,h0.y,h0.z,h0.w,h1.x,h1.y,h1.z,h1.w,
                   h2.x,h2.y,h2.z,h2.w,h3.x,h3.y,h3.z,h3.w};
    double p[RB];
    #pragma unroll
    for (int j=0;j<RB;j++){
      double a0=0, a1=0;
      #pragma unroll
      for (int q=0;q<8;q++){
        a0 = fma(hh[2*q],   mkr[j][2*q],   a0);
        a1 = fma(hh[2*q+1], mkr[j][2*q+1], a1);
      }
      p[j] = a0 + a1;
    }
    #pragma unroll
    for (int o=1;o<16;o<<=1)
      #pragma unroll
      for (int j=0;j<RB;j++) p[j] += __shfl_xor(p[j], o, 64);
    double v = (sl==0)? p[0] : (sl==1)? p[1] : (sl==2)? p[2] : p[3];
    v += __shfl_xor(v, 16, 64);
    v += __shfl_xor(v, 32, 64);
    acc += exp(v * (1.0/32.0)) * izl[rr];
  }
  red[t] = acc;
  __syncthreads();
  for (int o=128; o>=RB; o>>=1){
    if (t < o) red[t] += red[t+o];
    __syncthreads();
  }
  if (t < ns) partial[(size_t)(s0+t)*NCHUNK + blockIdx.y] = red[t];
}

// deterministic chunk-sum finish: imp[slot] = (sum_chunks partial)/16
__global__ __launch_bounds__(256) void k_repair_fin(const int* __restrict__ bandcnt,
    const int* __restrict__ bandidx, const double* __restrict__ partial, double* __restrict__ imp)
{
  int bc = *bandcnt; if (bc > BAND_CAP) bc = BAND_CAP;
  int slot = blockIdx.x*256 + threadIdx.x;
  if (slot >= bc) return;
  double s = 0;
  #pragma unroll
  for (int ch=0; ch<NCHUNK; ch++) s += partial[(size_t)slot*NCHUNK + ch];
  imp[bandidx[slot]] = s * 0.0625;
}

// PV fallback: in-loop MV conversion, split-K=4
__global__ __launch_bounds__(256) void k_pvm(const u16* __restrict__ P,
    const float* __restrict__ MV, float* __restrict__ O)
{
  __shared__ __align__(16) u16 Ap[128][40];
  __shared__ u32 Bv[16][132];
  int t=threadIdx.x, w=t>>6, g=(t>>4)&3, c=t&15;
  int row0=blockIdx.x*128, d0=blockIdx.y*128;
  size_t kb0 = (size_t)blockIdx.z*8192;
  int srow=t>>1, sq=(t&1)*16;
  int mp=t>>5, dc=t&31;
  f32x4 acc[2][8];
  #pragma unroll
  for (int fi=0;fi<2;fi++)
    #pragma unroll
    for (int fj=0;fj<8;fj++) acc[fi][fj] = (f32x4){0.f,0.f,0.f,0.f};
  const u16*  pg  = P  + (size_t)(row0+srow)*32768 + kb0 + sq;
  const float* mva = MV + (kb0 + 2*mp  )*1024 + d0 + dc;
  const float* mvb = mva + 1024;
  const float* mvc = mva + 16*1024;
  const float* mvd = mvc + 1024;
  uint4 pa0 = *(const uint4*)pg;
  uint4 pa1 = *(const uint4*)(pg + 8);
  float a0[4], b0[4], a1[4], b1[4];
  #pragma unroll
  for (int j=0;j<4;j++){ a0[j]=mva[32*j]; b0[j]=mvb[32*j]; a1[j]=mvc[32*j]; b1[j]=mvd[32*j]; }
  for (int kt=0; kt<256; kt++){
    __syncthreads();
    *(uint4*)&Ap[srow][sq]   = pa0;
    *(uint4*)&Ap[srow][sq+8] = pa1;
    #pragma unroll
    for (int j=0;j<4;j++){
      Bv[mp  ][dc+32*j] = (u32)f2bf(a0[j]) | ((u32)f2bf(b0[j])<<16);
      Bv[mp+8][dc+32*j] = (u32)f2bf(a1[j]) | ((u32)f2bf(b1[j])<<16);
    }
    __syncthreads();
    if (kt+1 < 256){
      size_t ko = (size_t)(kt+1)*32;
      pa0 = *(const uint4*)(pg + ko);
      pa1 = *(const uint4*)(pg + ko + 8);
      size_t fo = ko*1024;
      #pragma unroll
      for (int j=0;j<4;j++){
        a0[j]=mva[fo+32*j]; b0[j]=mvb[fo+32*j];
        a1[j]=mvc[fo+32*j]; b1[j]=mvd[fo+32*j];
      }
    }
    bf16x8 af[2];
    af[0] = *(const bf16x8*)&Ap[w*32 + c][g*8];
    af[1] = *(const bf16x8*)&Ap[w*32 + 16 + c][g*8];
    #pragma unroll
    for (int fj=0; fj<8; fj++){
      union { u32 u[4]; bf16x8 v; } bb;
      #pragma unroll
      for (int qq=0; qq<4; qq++) bb.u[qq] = Bv[4*g+qq][fj*16 + c];
      acc[0][fj] = MFMA16(af[0], bb.v, acc[0][fj]);
      acc[1][fj] = MFMA16(af[1], bb.v, acc[1][fj]);
    }
  }
  #pragma unroll
  for (int fi=0;fi<2;fi++)
    #pragma unroll
    for (int fj=0;fj<8;fj++)
      #pragma unroll
      for (int r=0;r<4;r++)
        atomicAdd(&O[(size_t)(row0 + w*32 + fi*16 + g*4 + r)*1024 + d0 + fj*16 + c],
                  acc[fi][fj][r]);
}

// PV fast (round-20 proven): 256-row tile (acc[4][8]), pre-packed MVT u32,
// cached P loads, split-K=4, NATURAL grid, single-buffer 2-barrier loop.
__global__ __launch_bounds__(256) void k_pvmp(const u16* __restrict__ P,
    const u32* __restrict__ MVT, float* __restrict__ O)
{
  __shared__ __align__(16) u16 Ap[256][40];   // 20 KB
  __shared__ u32 Bv[16][132];                  // 8.4 KB
  int t=threadIdx.x, w=t>>6, g=(t>>4)&3, c=t&15;
  int row0=blockIdx.x*256, d0=blockIdx.y*128;
  size_t kb0 = (size_t)blockIdx.z*8192;
  size_t pb0 = kb0 >> 1;
  int mp=t>>5, dc=t&31;
  f32x4 acc[4][8];
  #pragma unroll
  for (int fi=0;fi<4;fi++)
    #pragma unroll
    for (int fj=0;fj<8;fj++) acc[fi][fj] = (f32x4){0.f,0.f,0.f,0.f};
  const u16* pg   = P   + (size_t)(row0+t)*32768 + kb0;   // one row per thread
  const u32* mvt0 = MVT + (pb0 + mp    )*1024 + d0 + dc;
  const u32* mvt1 = MVT + (pb0 + 8 + mp)*1024 + d0 + dc;

  uint4 pa0 = *(const uint4*)(pg);
  uint4 pa1 = *(const uint4*)(pg + 8);
  uint4 pa2 = *(const uint4*)(pg + 16);
  uint4 pa3 = *(const uint4*)(pg + 24);
  u32 b0[4], b1[4];
  #pragma unroll
  for (int j=0;j<4;j++){ b0[j]=mvt0[32*j]; b1[j]=mvt1[32*j]; }

  for (int kt=0; kt<256; kt++){
    __syncthreads();
    *(uint4*)&Ap[t][0]  = pa0;
    *(uint4*)&Ap[t][8]  = pa1;
    *(uint4*)&Ap[t][16] = pa2;
    *(uint4*)&Ap[t][24] = pa3;
    #pragma unroll
    for (int j=0;j<4;j++){
      Bv[mp  ][dc+32*j] = b0[j];
      Bv[mp+8][dc+32*j] = b1[j];
    }
    __syncthreads();
    if (kt+1 < 256){
      size_t ko = (size_t)(kt+1)*32;
      pa0 = *(const uint4*)(pg + ko);
      pa1 = *(const uint4*)(pg + ko + 8);
      pa2 = *(const uint4*)(pg + ko + 16);
      pa3 = *(const uint4*)(pg + ko + 24);
      size_t fo = (size_t)(kt+1)*16*1024;
      #pragma unroll
      for (int j=0;j<4;j++){ b0[j]=mvt0[fo+32*j]; b1[j]=mvt1[fo+32*j]; }
    }
    bf16x8 af[4];
    af[0] = *(const bf16x8*)&Ap[w*64 + c][g*8];
    af[1] = *(const bf16x8*)&Ap[w*64 + 16 + c][g*8];
    af[2] = *(const bf16x8*)&Ap[w*64 + 32 + c][g*8];
    af[3] = *(const bf16x8*)&Ap[w*64 + 48 + c][g*8];
    #pragma unroll
    for (int fj=0; fj<8; fj++){
      union { u32 u[4]; bf16x8 v; } bb;
      #pragma unroll
      for (int qq=0; qq<4; qq++) bb.u[qq] = Bv[4*g+qq][fj*16 + c];
      acc[0][fj] = MFMA16(af[0], bb.v, acc[0][fj]);
      acc[1][fj] = MFMA16(af[1], bb.v, acc[1][fj]);
      acc[2][fj] = MFMA16(af[2], bb.v, acc[2][fj]);
      acc[3][fj] = MFMA16(af[3], bb.v, acc[3][fj]);
    }
  }
  #pragma unroll
  for (int fi=0;fi<4;fi++)
    #pragma unroll
    for (int fj=0;fj<8;fj++)
      #pragma unroll
      for (int r=0;r<4;r++)
        atomicAdd(&O[(size_t)(row0 + w*64 + fi*16 + g*4 + r)*1024 + d0 + fj*16 + c],
                  acc[fi][fj][r]);
}

// out-proj via 1-pass bf16 MFMA
__global__ __launch_bounds__(256) void k_projm(const float* __restrict__ X,
    const float* __restrict__ W, const float* __restrict__ bias, float* __restrict__ Y)
{
  __shared__ __align__(16) u16 ldsbuf[2*128*40];
  u16 (*Ah)[40]=(u16(*)[40])(ldsbuf);
  u16 (*Bh)[40]=(u16(*)[40])(ldsbuf+128*40);
  int t=threadIdx.x, w=t>>6, g=(t>>4)&3, c=t&15;
  int row0=blockIdx.y*128, col0=blockIdx.x*128;
  f32x4 acc[2][8];
  #pragma unroll
  for (int fi=0;fi<2;fi++)
    #pragma unroll
    for (int fj=0;fj<8;fj++) acc[fi][fj] = (f32x4){0.f,0.f,0.f,0.f};
  sweep_core<false>(X, W, row0, col0, Ah, Ah, Bh, acc);
  #pragma unroll
  for (int fi=0;fi<2;fi++)
    #pragma unroll
    for (int fj=0;fj<8;fj++){
      float bb = bias[col0 + fj*16 + c];
      #pragma unroll
      for (int r=0;r<4;r++)
        Y[(size_t)(row0 + w*32 + fi*16 + g*4 + r)*1024 + col0 + fj*16 + c]
          = acc[fi][fj][r] + bb;
    }
}

__global__ __launch_bounds__(256) void k_scatter(const float* __restrict__ mk, const float* __restrict__ mv,
    const float* __restrict__ mage, const float* __restrict__ krow, const float* __restrict__ vrow,
    const int* __restrict__ sel, float* __restrict__ nk, float* __restrict__ nv,
    float* __restrict__ na, int* __restrict__ usage)
{
  int s = blockIdx.x, t = threadIdx.x;
  bool is = sel[s] != 0;
  const float2* sk = (const float2*)krow;
  const float2* sv = (const float2*)vrow;
  const float2* ok = (const float2*)(mk + (size_t)s*1024);
  const float2* ov = (const float2*)(mv + (size_t)s*1024);
  float2* dk = (float2*)(nk + (size_t)s*1024);
  float2* dv = (float2*)(nv + (size_t)s*1024);
  #pragma unroll
  for (int q=t;q<512;q+=256){
    dk[q] = is ? sk[q] : ok[q];
    dv[q] = is ? sv[q] : ov[q];
  }
  if (t==0){
    float a = mage[s] + 1.0f;
    float nav = is ? 0.0f : a;
    na[s] = nav;
    if (nav > 0.0f) atomicAdd(usage, 1);
  }
}

__global__ __launch_bounds__(256) void k_fin(const float* __restrict__ rowmax, const int* __restrict__ cnt,
    const int* __restrict__ usage, float* __restrict__ acc_out, float* __restrict__ scal)
{
  int t = threadIdx.x;
  __shared__ double sd[256];
  double s = 0;
  for (int r=t;r<4096;r+=256) s += (double)rowmax[r];
  sd[t]=s; __syncthreads();
  for (int o=128;o>0;o>>=1){ if (t<o) sd[t]+=sd[t+o]; __syncthreads(); }
  if (t==0){
    scal[0] = (float)(sd[0] / 4096.0);
    scal[1] = (float)((double)(*usage) / 32768.0);
  }
  for (int m=t;m<32768;m+=256) acc_out[m] = (float)cnt[m];
}

extern "C" void kernel_launch(void* const* d_in, const int* in_sizes, int n_in,
                              void* d_out, int out_size, void* d_ws, size_t ws_size,
                              hipStream_t stream) {
  const float* hs  = (const float*)d_in[0];
  const float* Wq  = (const float*)d_in[1];
  const float* bq  = (const float*)d_in[2];
  const float* Wk  = (const float*)d_in[3];
  const float* bk  = (const float*)d_in[4];
  const float* Wv  = (const float*)d_in[5];
  const float* bv  = (const float*)d_in[6];
  const float* Wo  = (const float*)d_in[7];
  const float* bo  = (const float*)d_in[8];
  const float* mk  = (const float*)d_in[9];
  const float* mv  = (const float*)d_in[10];
  const float* mage= (const float*)d_in[11];
  float* out = (float*)d_out;

  char* ws = (char*)d_ws;
  const size_t MB = 1024*1024;
  bool fast = ws_size >= 82*MB;
  size_t stats_off = fast ? 80*MB : 16*MB;
  char* st = ws + stats_off;

  double* Zrow   = (double*)(st);            // 4096 f64
  u32*    rmk    = (u32*)  (st + 32768);     // 4096
  float*  invZ   = (float*)(st + 49152);     // 4096
  double* invZd  = (double*)(st + 65536);    // 4096 f64
  float*  rowmax = (float*)(st + 98304);     // 4096
  double* imp    = (double*)(st + 114688);   // 32768 f64
  int*    cnt    = (int*)  (st + 376832);    // 32768
  int*    sel    = (int*)  (st + 507904);    // 32768
  float*  krow   = (float*)(st + 638976);    // 1024
  float*  vrow   = (float*)(st + 643072);    // 1024
  int*    usage  = (int*)  (st + 647168);    // 1
  double* vstar  = (double*)(st + 647176);   // 1 f64
  int*    bandcnt= (int*)  (st + 647184);    // 1
  int*    bandidx= (int*)  (st + 647188);    // 8192
  double* partial= (double*)(st + 680960);   // BAND_CAP*NCHUNK f64 = 512KB

  float* O   = (float*)ws;                   // [0:16M) (zeroed before PV)
  u16*   Qh  = (u16*)ws;                     // fast: [0:8M)
  u16*   MKh = (u16*)(ws + 16*MB);           // fast: [16M:80M)
  u32*   MVT = (u32*)(ws + 16*MB);           // fast: same region, after MKh dead

  float* Qhi = (float*)d_out;
  u16*   P   = (u16*)((char*)d_out + 16908544);

  dim3 blk(256);
  if (fast){
    hipMemsetAsync(st, 0, 647188 + BAND_CAP*4, stream);
    k_projq64<<<dim3(16,64),blk,0,stream>>>(hs, Wq, bq, Qhi, Qh, nullptr);
    k_cvt_mk<<<8192,blk,0,stream>>>(mk, MKh);
    k_rowproj<<<2048,blk,0,stream>>>(hs, Wk, bk, Wv, bv, krow, vrow);
    k_sweep1p<<<dim3(256,16),blk,0,stream>>>(Qh, MKh, Zrow, rmk);
    k_invz<<<16,blk,0,stream>>>(Zrow, rmk, invZ, invZd, rowmax);
    k_sweep2p<<<dim3(256,16),blk,0,stream>>>(Qh, MKh, invZ, imp, cnt, P);
    hipMemsetAsync(ws, 0, 16*MB, stream);
    k_cvt_mvt<<<16384,blk,0,stream>>>(mv, MVT);
    k_select<0><<<1,1024,0,stream>>>(imp, mage, vstar, nullptr);
    k_band<<<128,blk,0,stream>>>(imp, mage, vstar, bandcnt, bandidx);
    k_repair2<<<dim3(BAND_CAP/RB, NCHUNK),blk,0,stream>>>(bandcnt, bandidx, Qhi, mk, invZd, partial);
    k_repair_fin<<<BAND_CAP/256,blk,0,stream>>>(bandcnt, bandidx, partial, imp);
    k_pvmp<<<dim3(16,8,4),blk,0,stream>>>(P, MVT, O);
    k_projm<<<dim3(8,32),blk,0,stream>>>(O, Wo, bo, out);
    k_select<1><<<1,1024,0,stream>>>(imp, mage, nullptr, sel);
    k_scatter<<<32768,blk,0,stream>>>(mk, mv, mage, krow, vrow, sel,
        out + 4227074, out + 37781506, out + 71335938, usage);
    k_fin<<<1,blk,0,stream>>>(rowmax, cnt, usage, out + 4194304, out + 4227072);
  } else {
    hipMemsetAsync(ws, 0, 16*MB + 647188 + BAND_CAP*4, stream);
    k_projq64<<<dim3(16,64),blk,0,stream>>>(hs, Wq, bq, Qhi, nullptr, nullptr);
    k_rowproj<<<2048,blk,0,stream>>>(hs, Wk, bk, Wv, bv, krow, vrow);
    k_sweep1m<<<dim3(256,32),blk,0,stream>>>(Qhi, mk, Zrow, rmk);
    k_invz<<<16,blk,0,stream>>>(Zrow, rmk, invZ, invZd, rowmax);
    k_sweep2m<<<dim3(256,32),blk,0,stream>>>(Qhi, mk, invZ, imp, cnt, P);
    k_select<0><<<1,1024,0,stream>>>(imp, mage, vstar, nullptr);
    k_band<<<128,blk,0,stream>>>(imp, mage, vstar, bandcnt, bandidx);
    k_repair2<<<dim3(BAND_CAP/RB, NCHUNK),blk,0,stream>>>(bandcnt, bandidx, Qhi, mk, invZd, partial);
    k_repair_fin<<<BAND_CAP/256,blk,0,stream>>>(bandcnt, bandidx, partial, imp);
    k_pvm<<<dim3(32,8,4),blk,0,stream>>>(P, mv, O);
    k_projm<<<dim3(8,32),blk,0,stream>>>(O, Wo, bo, out);
    k_select<1><<<1,1024,0,stream>>>(imp, mage, nullptr, sel);
    k_scatter<<<32768,blk,0,stream>>>(mk, mv, mage, krow, vrow, sel,
        out + 4227074, out + 37781506, out + 71335938, usage);
    k_fin<<<1,blk,0,stream>>>(rowmax, cnt, usage, out + 4194304, out + 4227072);
  }
}

// Round 22
// 2419.101 us; speedup vs baseline: 1.2066x; 1.2066x over previous
//
#include <hip/hip_runtime.h>

// MemoryBlock: B=4,S=1024,H=1024,M=32768,NH=1.  rows R=B*S=4096, D=1024, M=32768
#define SCALE 0.03125f  // 1/sqrt(1024) exact
#define BAND_EPS 1e-6
#define BAND_CAP 8192
#define RB 4            // band slots per repair block
#define NCHUNK 8        // row chunks (4096/512) for repair parallelism

typedef unsigned int u32;
typedef unsigned short u16;
typedef unsigned long long u64;
typedef __attribute__((ext_vector_type(8))) short bf16x8;
typedef __attribute__((ext_vector_type(4))) float f32x4;

#define MFMA16(A,B,C) __builtin_amdgcn_mfma_f32_16x16x32_bf16(A,B,C,0,0,0)

__device__ __forceinline__ u32 fenc(float x){ u32 u=__float_as_uint(x); return (u&0x80000000u)? ~u : (u|0x80000000u); }
__device__ __forceinline__ float fdec(u32 e){ return (e&0x80000000u)? __uint_as_float(e&0x7FFFFFFFu) : __uint_as_float(~e); }
__device__ __forceinline__ u16 f2bf(float f){ u32 u=__float_as_uint(f); u32 r=(u + 0x7FFFu + ((u>>16)&1u))>>16; return (u16)r; }
__device__ __forceinline__ float bf2f(u16 h){ return __uint_as_float(((u32)h)<<16); }

// Q projection in f64 -> Qhi f32; optionally bf16 hi (and lo if Ql != null)
__global__ __launch_bounds__(256) void k_projq64(const float* __restrict__ X, const float* __restrict__ W,
    const float* __restrict__ bias, float* __restrict__ Qhi, u16* __restrict__ Qh, u16* __restrict__ Ql)
{
  __shared__ float Xs[16][68], Ws[16][68];
  int t=threadIdx.x, ty=t>>4, tx=t&15;
  int row0=blockIdx.y*64, col0=blockIdx.x*64;
  int lr=t>>2, lk=(t&3)*4;
  double acc[4][4]={};
  for (int k0=0;k0<1024;k0+=16){
    __syncthreads();
    {
      float4 x = *(const float4*)(X + (size_t)(row0+lr)*1024 + k0 + lk);
      float4 w = *(const float4*)(W + (size_t)(col0+lr)*1024 + k0 + lk);
      Xs[lk+0][lr]=x.x; Xs[lk+1][lr]=x.y; Xs[lk+2][lr]=x.z; Xs[lk+3][lr]=x.w;
      Ws[lk+0][lr]=w.x; Ws[lk+1][lr]=w.y; Ws[lk+2][lr]=w.z; Ws[lk+3][lr]=w.w;
    }
    __syncthreads();
    #pragma unroll
    for (int kk=0;kk<16;kk++){
      double a[4], b[4];
      #pragma unroll
      for (int i=0;i<4;i++) a[i] = (double)Xs[kk][ty*4+i];
      #pragma unroll
      for (int j=0;j<4;j++) b[j] = (double)Ws[kk][tx*4+j];
      #pragma unroll
      for (int i=0;i<4;i++)
        #pragma unroll
        for (int j=0;j<4;j++)
          acc[i][j] = fma(a[i], b[j], acc[i][j]);
    }
  }
  #pragma unroll
  for (int i=0;i<4;i++)
    #pragma unroll
    for (int j=0;j<4;j++){
      double q = acc[i][j] + (double)bias[col0+tx*4+j];
      float hi = (float)q;
      size_t off = (size_t)(row0+ty*4+i)*1024 + col0 + tx*4 + j;
      Qhi[off] = hi;
      if (Qh){
        u16 h = f2bf(hi);
        Qh[off] = h;
        if (Ql) Ql[off] = f2bf(hi - bf2f(h));
      }
    }
}

// single-row projection (f64): k[0,-1], v[0,-1] (hs flat row 1023)
__global__ __launch_bounds__(256) void k_rowproj(const float* __restrict__ hs,
    const float* __restrict__ Wk, const float* __restrict__ bk,
    const float* __restrict__ Wv, const float* __restrict__ bv,
    float* __restrict__ krow, float* __restrict__ vrow)
{
  int b = blockIdx.x; int which = b >> 10; int o = b & 1023; int t = threadIdx.x;
  const float* W = which ? Wv : Wk;
  const float* bias = which ? bv : bk;
  const float* x = hs + (size_t)1023*1024;
  double s = 0;
  for (int k=t;k<1024;k+=256) s += (double)x[k] * (double)W[(size_t)o*1024+k];
  __shared__ double sd[256];
  sd[t]=s; __syncthreads();
  for (int off=128;off>0;off>>=1){ if(t<off) sd[t]+=sd[t+off]; __syncthreads(); }
  if (t==0){ float* dst = which? vrow : krow; dst[o] = (float)(sd[0] + (double)bias[o]); }
}

// f32 -> bf16 bulk convert (16 elems/thread)
__global__ __launch_bounds__(256) void k_cvt_mk(const float* __restrict__ src, u16* __restrict__ dst)
{
  size_t base = ((size_t)blockIdx.x*256 + threadIdx.x) * 16;
  float v[16];
  #pragma unroll
  for (int q=0;q<4;q++) *(float4*)&v[q*4] = *(const float4*)(src + base + q*4);
  u16 h[16];
  #pragma unroll
  for (int q=0;q<16;q++) h[q] = f2bf(v[q]);
  *(uint4*)(dst+base)   = *(uint4*)&h[0];
  *(uint4*)(dst+base+8) = *(uint4*)&h[8];
}

// MV -> MVT[mpair][d] u32 = bf16(MV[2mp][d]) | bf16(MV[2mp+1][d])<<16
__global__ __launch_bounds__(256) void k_cvt_mvt(const float* __restrict__ MV, u32* __restrict__ MVT)
{
  size_t mp = blockIdx.x; int d = threadIdx.x*4;
  float4 r0 = *(const float4*)(MV + (2*mp  )*1024 + d);
  float4 r1 = *(const float4*)(MV + (2*mp+1)*1024 + d);
  u32 o[4];
  o[0] = (u32)f2bf(r0.x) | ((u32)f2bf(r1.x)<<16);
  o[1] = (u32)f2bf(r0.y) | ((u32)f2bf(r1.y)<<16);
  o[2] = (u32)f2bf(r0.z) | ((u32)f2bf(r1.z)<<16);
  o[3] = (u32)f2bf(r0.w) | ((u32)f2bf(r1.w)<<16);
  *(uint4*)(MVT + mp*1024 + d) = *(uint4*)o;
}

// ---------- MFMA core, in-loop f32->bf16 conversion (fallback path) ----------
template<bool SPLIT>
__device__ __forceinline__ void sweep_core(
    const float* __restrict__ Qg, const float* __restrict__ MKg,
    int row0, int col0,
    u16 (*Ah)[40], u16 (*Al)[40], u16 (*Bh)[40],
    f32x4 acc[2][8])
{
  int t = threadIdx.x;
  int w = t >> 6, g = (t >> 4) & 3, c = t & 15;
  int srow = t >> 1, sq = (t & 1) * 16;
  const float* xg = Qg  + (size_t)(row0 + srow)*1024 + sq;
  const float* wg = MKg + (size_t)(col0 + srow)*1024 + sq;
  float xr[16], wr[16];
  #pragma unroll
  for (int q=0;q<4;q++){
    *(float4*)&xr[q*4] = *(const float4*)(xg + q*4);
    *(float4*)&wr[q*4] = *(const float4*)(wg + q*4);
  }
  for (int k0 = 0; k0 < 1024; k0 += 32){
    u16 ah[16], al[16], bh[16];
    #pragma unroll
    for (int q=0;q<16;q++){
      u16 h = f2bf(xr[q]); ah[q]=h;
      bh[q] = f2bf(wr[q]);
      if constexpr (SPLIT) al[q]=f2bf(xr[q]-bf2f(h));
    }
    __syncthreads();
    *(uint4*)&Ah[srow][sq]   = *(uint4*)&ah[0];
    *(uint4*)&Ah[srow][sq+8] = *(uint4*)&ah[8];
    *(uint4*)&Bh[srow][sq]   = *(uint4*)&bh[0];
    *(uint4*)&Bh[srow][sq+8] = *(uint4*)&bh[8];
    if constexpr (SPLIT){
      *(uint4*)&Al[srow][sq]   = *(uint4*)&al[0];
      *(uint4*)&Al[srow][sq+8] = *(uint4*)&al[8];
    }
    __syncthreads();
    if (k0 + 32 < 1024){
      #pragma unroll
      for (int q=0;q<4;q++){
        *(float4*)&xr[q*4] = *(const float4*)(xg + k0+32 + q*4);
        *(float4*)&wr[q*4] = *(const float4*)(wg + k0+32 + q*4);
      }
    }
    bf16x8 afh[2], afl[2];
    #pragma unroll
    for (int fi=0; fi<2; fi++){
      afh[fi] = *(const bf16x8*)&Ah[w*32 + fi*16 + c][g*8];
      if constexpr (SPLIT) afl[fi] = *(const bf16x8*)&Al[w*32 + fi*16 + c][g*8];
    }
    #pragma unroll
    for (int fj=0; fj<8; fj++){
      bf16x8 bfh = *(const bf16x8*)&Bh[fj*16 + c][g*8];
      #pragma unroll
      for (int fi=0; fi<2; fi++){
        acc[fi][fj] = MFMA16(afh[fi], bfh, acc[fi][fj]);
        if constexpr (SPLIT)
          acc[fi][fj] = MFMA16(afl[fi], bfh, acc[fi][fj]);
      }
    }
  }
}

// ---------- MFMA core, pre-converted bf16 inputs (fast path, 128-tile) -------
template<bool SPLIT>
__device__ __forceinline__ void sweep_core_pre(
    const u16* __restrict__ Ag, const u16* __restrict__ Alg, const u16* __restrict__ Bg,
    int row0, int col0,
    u16 (*Ah)[40], u16 (*Al)[40], u16 (*Bh)[40],
    f32x4 acc[2][8])
{
  int t = threadIdx.x;
  int w = t >> 6, g = (t >> 4) & 3, c = t & 15;
  int srow = t >> 1, sq = (t & 1) * 16;
  const u16* xa = Ag + (size_t)(row0+srow)*1024 + sq;
  const u16* wb = Bg + (size_t)(col0+srow)*1024 + sq;
  const u16* xl = Alg + (size_t)(row0+srow)*1024 + sq;
  uint4 a0 = *(const uint4*)xa, a1 = *(const uint4*)(xa+8);
  uint4 b0 = *(const uint4*)wb, b1 = *(const uint4*)(wb+8);
  uint4 l0, l1;
  if constexpr (SPLIT){ l0 = *(const uint4*)xl; l1 = *(const uint4*)(xl+8); }
  for (int k0 = 0; k0 < 1024; k0 += 32){
    __syncthreads();
    *(uint4*)&Ah[srow][sq]   = a0;
    *(uint4*)&Ah[srow][sq+8] = a1;
    *(uint4*)&Bh[srow][sq]   = b0;
    *(uint4*)&Bh[srow][sq+8] = b1;
    if constexpr (SPLIT){
      *(uint4*)&Al[srow][sq]   = l0;
      *(uint4*)&Al[srow][sq+8] = l1;
    }
    __syncthreads();
    if (k0 + 32 < 1024){
      a0=*(const uint4*)(xa+k0+32); a1=*(const uint4*)(xa+k0+40);
      b0=*(const uint4*)(wb+k0+32); b1=*(const uint4*)(wb+k0+40);
      if constexpr (SPLIT){ l0=*(const uint4*)(xl+k0+32); l1=*(const uint4*)(xl+k0+40); }
    }
    bf16x8 afh[2], afl[2];
    #pragma unroll
    for (int fi=0; fi<2; fi++){
      afh[fi] = *(const bf16x8*)&Ah[w*32 + fi*16 + c][g*8];
      if constexpr (SPLIT) afl[fi] = *(const bf16x8*)&Al[w*32 + fi*16 + c][g*8];
    }
    #pragma unroll
    for (int fj=0; fj<8; fj++){
      bf16x8 bfh = *(const bf16x8*)&Bh[fj*16 + c][g*8];
      #pragma unroll
      for (int fi=0; fi<2; fi++){
        acc[fi][fj] = MFMA16(afh[fi], bfh, acc[fi][fj]);
        if constexpr (SPLIT)
          acc[fi][fj] = MFMA16(afl[fi], bfh, acc[fi][fj]);
      }
    }
  }
}

// sweep1 epilogue (shared): rowmax + Z
__device__ __forceinline__ void sweep1_epi(f32x4 acc[2][8], int row0,
    double* Zrow, u32* rmk)
{
  int t=threadIdx.x, w=t>>6, g=(t>>4)&3, c=t&15;
  #pragma unroll
  for (int fi=0;fi<2;fi++){
    #pragma unroll
    for (int r=0;r<4;r++){
      float mx=-1e30f, sm=0.f;
      #pragma unroll
      for (int fj=0;fj<8;fj++){
        float sc = acc[fi][fj][r]*SCALE;
        mx = fmaxf(mx, sc);
        sm += expf(sc);
      }
      #pragma unroll
      for (int o=1;o<16;o<<=1){
        mx = fmaxf(mx, __shfl_xor(mx,o,64));
        sm += __shfl_xor(sm,o,64);
      }
      if (c==0){
        int row = row0 + w*32 + fi*16 + g*4 + r;
        atomicMax(&rmk[row], fenc(mx));
        atomicAdd(&Zrow[row], (double)sm);
      }
    }
  }
}

__global__ __launch_bounds__(256) void k_sweep1m(const float* __restrict__ Q,
    const float* __restrict__ MK, double* __restrict__ Zrow, u32* __restrict__ rmk)
{
  __shared__ __align__(16) u16 ldsbuf[2*128*40];
  u16 (*Ah)[40]=(u16(*)[40])(ldsbuf);
  u16 (*Bh)[40]=(u16(*)[40])(ldsbuf+128*40);
  int row0=blockIdx.y*128, col0=blockIdx.x*128;
  f32x4 acc[2][8];
  #pragma unroll
  for (int fi=0;fi<2;fi++)
    #pragma unroll
    for (int fj=0;fj<8;fj++) acc[fi][fj] = (f32x4){0.f,0.f,0.f,0.f};
  sweep_core<false>(Q, MK, row0, col0, Ah, Ah, Bh, acc);
  sweep1_epi(acc, row0, Zrow, rmk);
}

__global__ __launch_bounds__(256) void k_sweep1p(const u16* __restrict__ Qh,
    const u16* __restrict__ MKh, double* __restrict__ Zrow, u32* __restrict__ rmk)
{
  __shared__ __align__(16) u16 ldsbuf[2*128*40];
  u16 (*Ah)[40]=(u16(*)[40])(ldsbuf);
  u16 (*Bh)[40]=(u16(*)[40])(ldsbuf+128*40);
  int row0=blockIdx.y*128, col0=blockIdx.x*128;
  f32x4 acc[2][8];
  #pragma unroll
  for (int fi=0;fi<2;fi++)
    #pragma unroll
    for (int fj=0;fj<8;fj++) acc[fi][fj] = (f32x4){0.f,0.f,0.f,0.f};
  sweep_core_pre<false>(Qh, Qh, MKh, row0, col0, Ah, Ah, Bh, acc);
  sweep1_epi(acc, row0, Zrow, rmk);
}

__global__ __launch_bounds__(256) void k_invz(const double* __restrict__ Z, const u32* __restrict__ rmk,
    float* __restrict__ invZ, double* __restrict__ invZd, float* __restrict__ rowmax)
{
  int r = blockIdx.x*256 + threadIdx.x;
  double iz = 1.0 / Z[r];
  invZ[r] = (float)iz;
  invZd[r] = iz;
  rowmax[r] = fdec(rmk[r]);
}

// sweep2 epilogue (shared): p, NT P store, f64 col-sums, counts
__device__ __forceinline__ void sweep2_epi(f32x4 acc[2][8], int row0, int col0,
    const float* invZ, double* imp, int* cnt, u16* P, u16* ldsbuf)
{
  int t=threadIdx.x, w=t>>6, g=(t>>4)&3, c=t&15;
  double colp[8]={0,0,0,0,0,0,0,0};
  int    colc[8]={0,0,0,0,0,0,0,0};
  #pragma unroll
  for (int fi=0;fi<2;fi++){
    float iz[4];
    #pragma unroll
    for (int r=0;r<4;r++) iz[r] = invZ[row0 + w*32 + fi*16 + g*4 + r];
    #pragma unroll
    for (int fj=0;fj<8;fj++){
      #pragma unroll
      for (int r=0;r<4;r++){
        float p = expf(acc[fi][fj][r]*SCALE)*iz[r];
        int row = row0 + w*32 + fi*16 + g*4 + r;
        __builtin_nontemporal_store(f2bf(p), &P[(size_t)row*32768 + col0 + fj*16 + c]);
        colp[fj] += (double)p;
        colc[fj] += (p > 0.01f) ? 1 : 0;
      }
    }
  }
  __syncthreads();
  double (*red)[128] = (double(*)[128])ldsbuf;
  #pragma unroll
  for (int fj=0;fj<8;fj++) red[w*4+g][fj*16+c] = colp[fj];
  __syncthreads();
  if (t < 128){
    double s=0;
    #pragma unroll
    for (int q=0;q<16;q++) s += red[q][t];
    atomicAdd(&imp[col0+t], s);
  }
  __syncthreads();
  #pragma unroll
  for (int fj=0;fj<8;fj++) red[w*4+g][fj*16+c] = (double)colc[fj];
  __syncthreads();
  if (t < 128){
    double s=0;
    #pragma unroll
    for (int q=0;q<16;q++) s += red[q][t];
    int ci = (int)(s+0.5);
    if (ci) atomicAdd(&cnt[col0+t], ci);
  }
}

__global__ __launch_bounds__(256) void k_sweep2m(const float* __restrict__ Q,
    const float* __restrict__ MK, const float* __restrict__ invZ,
    double* __restrict__ imp, int* __restrict__ cnt, u16* __restrict__ P)
{
  __shared__ __align__(16) u16 ldsbuf[3*128*40];
  u16 (*Ah)[40]=(u16(*)[40])(ldsbuf);
  u16 (*Al)[40]=(u16(*)[40])(ldsbuf+128*40);
  u16 (*Bh)[40]=(u16(*)[40])(ldsbuf+2*128*40);
  int row0=blockIdx.y*128, col0=blockIdx.x*128;
  f32x4 acc[2][8];
  #pragma unroll
  for (int fi=0;fi<2;fi++)
    #pragma unroll
    for (int fj=0;fj<8;fj++) acc[fi][fj] = (f32x4){0.f,0.f,0.f,0.f};
  sweep_core<true>(Q, MK, row0, col0, Ah, Al, Bh, acc);
  sweep2_epi(acc, row0, col0, invZ, imp, cnt, P, ldsbuf);
}

// fast-path sweep2: 1-pass bf16 (Qh.MKh); band repair fixes boundary slots in f64.
__global__ __launch_bounds__(256) void k_sweep2p(const u16* __restrict__ Qh,
    const u16* __restrict__ MKh, const float* __restrict__ invZ,
    double* __restrict__ imp, int* __restrict__ cnt, u16* __restrict__ P)
{
  __shared__ __align__(16) u16 ldsbuf[2*128*40];
  u16 (*Ah)[40]=(u16(*)[40])(ldsbuf);
  u16 (*Bh)[40]=(u16(*)[40])(ldsbuf+128*40);
  int row0=blockIdx.y*128, col0=blockIdx.x*128;
  f32x4 acc[2][8];
  #pragma unroll
  for (int fi=0;fi<2;fi++)
    #pragma unroll
    for (int fj=0;fj<8;fj++) acc[fi][fj] = (f32x4){0.f,0.f,0.f,0.f};
  sweep_core_pre<false>(Qh, Qh, MKh, row0, col0, Ah, Ah, Bh, acc);
  sweep2_epi(acc, row0, col0, invZ, imp, cnt, P, ldsbuf);
}

// ---------------- single-block radix select on f32 vals ---------------------
template<int MODE>
__global__ __launch_bounds__(1024) void k_select(const double* __restrict__ imp,
    const float* __restrict__ mage, double* __restrict__ vsout, int* __restrict__ sel)
{
  __shared__ int hist[256];
  __shared__ int scanbuf[1024];
  __shared__ u32 s_digit; __shared__ int s_rr;
  int t = threadIdx.x;
  int m0 = t*32;
  u32 key[32];
  #pragma unroll
  for (int i=0;i<32;i++){
    int m = m0+i;
    float v = (mage[m] + 1.0f) + (1.0f - (float)imp[m]);
    key[i] = fenc(v);
  }
  u32 prefix = 0, pmask = 0;
  int rr = 1024;
  for (int pass=0; pass<4; pass++){
    int shift = 24 - pass*8;
    if (t<256) hist[t]=0;
    __syncthreads();
    #pragma unroll
    for (int i=0;i<32;i++){
      if ((key[i] & pmask) == prefix)
        atomicAdd(&hist[(key[i]>>shift)&255u], 1);
    }
    __syncthreads();
    if (t==0){
      int cum=0; int d=255;
      for (; d>0; d--){
        if (cum + hist[d] >= rr) break;
        cum += hist[d];
      }
      s_rr = rr - cum;
      s_digit = (u32)d;
    }
    __syncthreads();
    rr = s_rr;
    prefix |= (s_digit << shift);
    pmask  |= (255u << shift);
    __syncthreads();
  }
  u32 keystar = prefix;
  int krem = rr;
  if (MODE==0){
    if (t==0) *vsout = (double)fdec(keystar);
    return;
  }
  int lc = 0;
  #pragma unroll
  for (int i=0;i<32;i++) lc += (key[i]==keystar) ? 1 : 0;
  scanbuf[t] = lc;
  __syncthreads();
  for (int off=1; off<1024; off<<=1){
    int v_ = scanbuf[t];
    int add = (t>=off)? scanbuf[t-off] : 0;
    __syncthreads();
    scanbuf[t] = v_ + add;
    __syncthreads();
  }
  int run = scanbuf[t] - lc;
  #pragma unroll
  for (int i=0;i<32;i++){
    int s_;
    if (key[i] > keystar) s_ = 1;
    else if (key[i] == keystar){ s_ = (run < krem) ? 1 : 0; run++; }
    else s_ = 0;
    sel[m0+i] = s_;
  }
}

__global__ __launch_bounds__(256) void k_band(const double* __restrict__ imp,
    const float* __restrict__ mage, const double* __restrict__ vsp,
    int* __restrict__ bandcnt, int* __restrict__ bandidx)
{
  int m = blockIdx.x*256 + threadIdx.x;
  double v = ((double)mage[m] + 1.0) + (1.0 - imp[m]);
  double vs = *vsp;
  if (fabs(v - vs) <= BAND_EPS){
    int idx = atomicAdd(bandcnt, 1);
    if (idx < BAND_CAP) bandidx[idx] = m;
  }
}

// exact importance for band slots: RB=4 slots x 512-row chunk per block.
__global__ __launch_bounds__(256) void k_repair2(const int* __restrict__ bandcnt, const int* __restrict__ bandidx,
    const float* __restrict__ Qhi, const float* __restrict__ MK,
    const double* __restrict__ invZd, double* __restrict__ partial)
{
  int bc = *bandcnt; if (bc > BAND_CAP) bc = BAND_CAP;
  int s0 = blockIdx.x * RB;
  if (s0 >= bc) return;
  int ns = bc - s0; if (ns > RB) ns = RB;
  int r0 = blockIdx.y * 512;
  __shared__ float mks[RB][1024];   // 16KB
  __shared__ double izl[512];       // 4KB
  __shared__ double red[256];       // 2KB
  int t = threadIdx.x;
  for (int idx = t; idx < RB*1024; idx += 256){
    int j = idx >> 10, d = idx & 1023;
    mks[j][d] = (j < ns) ? MK[(size_t)bandidx[s0+j]*1024 + d] : 0.f;
  }
  for (int r = t; r < 512; r += 256) izl[r] = invZd[r0 + r];
  __syncthreads();
  int wave = t>>6, lane = t&63, d0 = lane*16, sl = lane&3;
  double mkr[RB][16];
  #pragma unroll
  for (int j=0;j<RB;j++)
    #pragma unroll
    for (int q=0;q<16;q++) mkr[j][q] = (double)mks[j][d0+q];
  double acc = 0;
  for (int rr = wave; rr < 512; rr += 4){
    const float4* hp = (const float4*)(Qhi + (size_t)(r0+rr)*1024 + d0);
    float4 h0=hp[0], h1=hp[1], h2=hp[2], h3=hp[3];
    double hh[16]={h0.x,h0.y,h0.z,h0.w,h1.x,h1.y,h1.z,h1.w,
                   h2.x,h2.y,h2.z,h2.w,h3.x,h3.y,h3.z,h3.w};
    double p[RB];
    #pragma unroll
    for (int j=0;j<RB;j++){
      double a0=0, a1=0;
      #pragma unroll
      for (int q=0;q<8;q++){
        a0 = fma(hh[2*q],   mkr[j][2*q],   a0);
        a1 = fma(hh[2*q+1], mkr[j][2*q+1], a1);
      }
      p[j] = a0 + a1;
    }
    #pragma unroll
    for (int o=1;o<16;o<<=1)
      #pragma unroll
      for (int j=0;j<RB;j++) p[j] += __shfl_xor(p[j], o, 64);
    double v = (sl==0)? p[0] : (sl==1)? p[1] : (sl==2)? p[2] : p[3];
    v += __shfl_xor(v, 16, 64);
    v += __shfl_xor(v, 32, 64);
    acc += exp(v * (1.0/32.0)) * izl[rr];
  }
  red[t] = acc;
  __syncthreads();
  for (int o=128; o>=RB; o>>=1){
    if (t < o) red[t] += red[t+o];
    __syncthreads();
  }
  if (t < ns) partial[(size_t)(s0+t)*NCHUNK + blockIdx.y] = red[t];
}

// deterministic chunk-sum finish: imp[slot] = (sum_chunks partial)/16
__global__ __launch_bounds__(256) void k_repair_fin(const int* __restrict__ bandcnt,
    const int* __restrict__ bandidx, const double* __restrict__ partial, double* __restrict__ imp)
{
  int bc = *bandcnt; if (bc > BAND_CAP) bc = BAND_CAP;
  int slot = blockIdx.x*256 + threadIdx.x;
  if (slot >= bc) return;
  double s = 0;
  #pragma unroll
  for (int ch=0; ch<NCHUNK; ch++) s += partial[(size_t)slot*NCHUNK + ch];
  imp[bandidx[slot]] = s * 0.0625;
}

// PV fallback: in-loop MV conversion, split-K=4
__global__ __launch_bounds__(256) void k_pvm(const u16* __restrict__ P,
    const float* __restrict__ MV, float* __restrict__ O)
{
  __shared__ __align__(16) u16 Ap[128][40];
  __shared__ u32 Bv[16][132];
  int t=threadIdx.x, w=t>>6, g=(t>>4)&3, c=t&15;
  int row0=blockIdx.x*128, d0=blockIdx.y*128;
  size_t kb0 = (size_t)blockIdx.z*8192;
  int srow=t>>1, sq=(t&1)*16;
  int mp=t>>5, dc=t&31;
  f32x4 acc[2][8];
  #pragma unroll
  for (int fi=0;fi<2;fi++)
    #pragma unroll
    for (int fj=0;fj<8;fj++) acc[fi][fj] = (f32x4){0.f,0.f,0.f,0.f};
  const u16*  pg  = P  + (size_t)(row0+srow)*32768 + kb0 + sq;
  const float* mva = MV + (kb0 + 2*mp  )*1024 + d0 + dc;
  const float* mvb = mva + 1024;
  const float* mvc = mva + 16*1024;
  const float* mvd = mvc + 1024;
  uint4 pa0 = *(const uint4*)pg;
  uint4 pa1 = *(const uint4*)(pg + 8);
  float a0[4], b0[4], a1[4], b1[4];
  #pragma unroll
  for (int j=0;j<4;j++){ a0[j]=mva[32*j]; b0[j]=mvb[32*j]; a1[j]=mvc[32*j]; b1[j]=mvd[32*j]; }
  for (int kt=0; kt<256; kt++){
    __syncthreads();
    *(uint4*)&Ap[srow][sq]   = pa0;
    *(uint4*)&Ap[srow][sq+8] = pa1;
    #pragma unroll
    for (int j=0;j<4;j++){
      Bv[mp  ][dc+32*j] = (u32)f2bf(a0[j]) | ((u32)f2bf(b0[j])<<16);
      Bv[mp+8][dc+32*j] = (u32)f2bf(a1[j]) | ((u32)f2bf(b1[j])<<16);
    }
    __syncthreads();
    if (kt+1 < 256){
      size_t ko = (size_t)(kt+1)*32;
      pa0 = *(const uint4*)(pg + ko);
      pa1 = *(const uint4*)(pg + ko + 8);
      size_t fo = ko*1024;
      #pragma unroll
      for (int j=0;j<4;j++){
        a0[j]=mva[fo+32*j]; b0[j]=mvb[fo+32*j];
        a1[j]=mvc[fo+32*j]; b1[j]=mvd[fo+32*j];
      }
    }
    bf16x8 af[2];
    af[0] = *(const bf16x8*)&Ap[w*32 + c][g*8];
    af[1] = *(const bf16x8*)&Ap[w*32 + 16 + c][g*8];
    #pragma unroll
    for (int fj=0; fj<8; fj++){
      union { u32 u[4]; bf16x8 v; } bb;
      #pragma unroll
      for (int qq=0; qq<4; qq++) bb.u[qq] = Bv[4*g+qq][fj*16 + c];
      acc[0][fj] = MFMA16(af[0], bb.v, acc[0][fj]);
      acc[1][fj] = MFMA16(af[1], bb.v, acc[1][fj]);
    }
  }
  #pragma unroll
  for (int fi=0;fi<2;fi++)
    #pragma unroll
    for (int fj=0;fj<8;fj++)
      #pragma unroll
      for (int r=0;r<4;r++)
        atomicAdd(&O[(size_t)(row0 + w*32 + fi*16 + g*4 + r)*1024 + d0 + fj*16 + c],
                  acc[fi][fj][r]);
}

// PV fast (round-20 proven): 256-row tile (acc[4][8]), pre-packed MVT u32,
// cached P loads, split-K=4, NATURAL grid, single-buffer 2-barrier loop.
__global__ __launch_bounds__(256) void k_pvmp(const u16* __restrict__ P,
    const u32* __restrict__ MVT, float* __restrict__ O)
{
  __shared__ __align__(16) u16 Ap[256][40];   // 20 KB
  __shared__ u32 Bv[16][132];                  // 8.4 KB
  int t=threadIdx.x, w=t>>6, g=(t>>4)&3, c=t&15;
  int row0=blockIdx.x*256, d0=blockIdx.y*128;
  size_t kb0 = (size_t)blockIdx.z*8192;
  size_t pb0 = kb0 >> 1;
  int mp=t>>5, dc=t&31;
  f32x4 acc[4][8];
  #pragma unroll
  for (int fi=0;fi<4;fi++)
    #pragma unroll
    for (int fj=0;fj<8;fj++) acc[fi][fj] = (f32x4){0.f,0.f,0.f,0.f};
  const u16* pg   = P   + (size_t)(row0+t)*32768 + kb0;   // one row per thread
  const u32* mvt0 = MVT + (pb0 + mp    )*1024 + d0 + dc;
  const u32* mvt1 = MVT + (pb0 + 8 + mp)*1024 + d0 + dc;

  uint4 pa0 = *(const uint4*)(pg);
  uint4 pa1 = *(const uint4*)(pg + 8);
  uint4 pa2 = *(const uint4*)(pg + 16);
  uint4 pa3 = *(const uint4*)(pg + 24);
  u32 b0[4], b1[4];
  #pragma unroll
  for (int j=0;j<4;j++){ b0[j]=mvt0[32*j]; b1[j]=mvt1[32*j]; }

  for (int kt=0; kt<256; kt++){
    __syncthreads();
    *(uint4*)&Ap[t][0]  = pa0;
    *(uint4*)&Ap[t][8]  = pa1;
    *(uint4*)&Ap[t][16] = pa2;
    *(uint4*)&Ap[t][24] = pa3;
    #pragma unroll
    for (int j=0;j<4;j++){
      Bv[mp  ][dc+32*j] = b0[j];
      Bv[mp+8][dc+32*j] = b1[j];
    }
    __syncthreads();
    if (kt+1 < 256){
      size_t ko = (size_t)(kt+1)*32;
      pa0 = *(const uint4*)(pg + ko);
      pa1 = *(const uint4*)(pg + ko + 8);
      pa2 = *(const uint4*)(pg + ko + 16);
      pa3 = *(const uint4*)(pg + ko + 24);
      size_t fo = (size_t)(kt+1)*16*1024;
      #pragma unroll
      for (int j=0;j<4;j++){ b0[j]=mvt0[fo+32*j]; b1[j]=mvt1[fo+32*j]; }
    }
    bf16x8 af[4];
    af[0] = *(const bf16x8*)&Ap[w*64 + c][g*8];
    af[1] = *(const bf16x8*)&Ap[w*64 + 16 + c][g*8];
    af[2] = *(const bf16x8*)&Ap[w*64 + 32 + c][g*8];
    af[3] = *(const bf16x8*)&Ap[w*64 + 48 + c][g*8];
    #pragma unroll
    for (int fj=0; fj<8; fj++){
      union { u32 u[4]; bf16x8 v; } bb;
      #pragma unroll
      for (int qq=0; qq<4; qq++) bb.u[qq] = Bv[4*g+qq][fj*16 + c];
      acc[0][fj] = MFMA16(af[0], bb.v, acc[0][fj]);
      acc[1][fj] = MFMA16(af[1], bb.v, acc[1][fj]);
      acc[2][fj] = MFMA16(af[2], bb.v, acc[2][fj]);
      acc[3][fj] = MFMA16(af[3], bb.v, acc[3][fj]);
    }
  }
  #pragma unroll
  for (int fi=0;fi<4;fi++)
    #pragma unroll
    for (int fj=0;fj<8;fj++)
      #pragma unroll
      for (int r=0;r<4;r++)
        atomicAdd(&O[(size_t)(row0 + w*64 + fi*16 + g*4 + r)*1024 + d0 + fj*16 + c],
                  acc[fi][fj][r]);
}

// out-proj via 1-pass bf16 MFMA
__global__ __launch_bounds__(256) void k_projm(const float* __restrict__ X,
    const float* __restrict__ W, const float* __restrict__ bias, float* __restrict__ Y)
{
  __shared__ __align__(16) u16 ldsbuf[2*128*40];
  u16 (*Ah)[40]=(u16(*)[40])(ldsbuf);
  u16 (*Bh)[40]=(u16(*)[40])(ldsbuf+128*40);
  int t=threadIdx.x, w=t>>6, g=(t>>4)&3, c=t&15;
  int row0=blockIdx.y*128, col0=blockIdx.x*128;
  f32x4 acc[2][8];
  #pragma unroll
  for (int fi=0;fi<2;fi++)
    #pragma unroll
    for (int fj=0;fj<8;fj++) acc[fi][fj] = (f32x4){0.f,0.f,0.f,0.f};
  sweep_core<false>(X, W, row0, col0, Ah, Ah, Bh, acc);
  #pragma unroll
  for (int fi=0;fi<2;fi++)
    #pragma unroll
    for (int fj=0;fj<8;fj++){
      float bb = bias[col0 + fj*16 + c];
      #pragma unroll
      for (int r=0;r<4;r++)
        Y[(size_t)(row0 + w*32 + fi*16 + g*4 + r)*1024 + col0 + fj*16 + c]
          = acc[fi][fj][r] + bb;
    }
}

__global__ __launch_bounds__(256) void k_scatter(const float* __restrict__ mk, const float* __restrict__ mv,
    const float* __restrict__ mage, const float* __restrict__ krow, const float* __restrict__ vrow,
    const int* __restrict__ sel, float* __restrict__ nk, float* __restrict__ nv,
    float* __restrict__ na, int* __restrict__ usage)
{
  int s = blockIdx.x, t = threadIdx.x;
  bool is = sel[s] != 0;
  const float2* sk = (const float2*)krow;
  const float2* sv = (const float2*)vrow;
  const float2* ok = (const float2*)(mk + (size_t)s*1024);
  const float2* ov = (const float2*)(mv + (size_t)s*1024);
  float2* dk = (float2*)(nk + (size_t)s*1024);
  float2* dv = (float2*)(nv + (size_t)s*1024);
  #pragma unroll
  for (int q=t;q<512;q+=256){
    dk[q] = is ? sk[q] : ok[q];
    dv[q] = is ? sv[q] : ov[q];
  }
  if (t==0){
    float a = mage[s] + 1.0f;
    float nav = is ? 0.0f : a;
    na[s] = nav;
    if (nav > 0.0f) atomicAdd(usage, 1);
  }
}

__global__ __launch_bounds__(256) void k_fin(const float* __restrict__ rowmax, const int* __restrict__ cnt,
    const int* __restrict__ usage, float* __restrict__ acc_out, float* __restrict__ scal)
{
  int t = threadIdx.x;
  __shared__ double sd[256];
  double s = 0;
  for (int r=t;r<4096;r+=256) s += (double)rowmax[r];
  sd[t]=s; __syncthreads();
  for (int o=128;o>0;o>>=1){ if (t<o) sd[t]+=sd[t+o]; __syncthreads(); }
  if (t==0){
    scal[0] = (float)(sd[0] / 4096.0);
    scal[1] = (float)((double)(*usage) / 32768.0);
  }
  for (int m=t;m<32768;m+=256) acc_out[m] = (float)cnt[m];
}

extern "C" void kernel_launch(void* const* d_in, const int* in_sizes, int n_in,
                              void* d_out, int out_size, void* d_ws, size_t ws_size,
                              hipStream_t stream) {
  const float* hs  = (const float*)d_in[0];
  const float* Wq  = (const float*)d_in[1];
  const float* bq  = (const float*)d_in[2];
  const float* Wk  = (const float*)d_in[3];
  const float* bk  = (const float*)d_in[4];
  const float* Wv  = (const float*)d_in[5];
  const float* bv  = (const float*)d_in[6];
  const float* Wo  = (const float*)d_in[7];
  const float* bo  = (const float*)d_in[8];
  const float* mk  = (const float*)d_in[9];
  const float* mv  = (const float*)d_in[10];
  const float* mage= (const float*)d_in[11];
  float* out = (float*)d_out;

  char* ws = (char*)d_ws;
  const size_t MB = 1024*1024;
  bool fast = ws_size >= 82*MB;
  size_t stats_off = fast ? 80*MB : 16*MB;
  char* st = ws + stats_off;

  double* Zrow   = (double*)(st);            // 4096 f64
  u32*    rmk    = (u32*)  (st + 32768);     // 4096
  float*  invZ   = (float*)(st + 49152);     // 4096
  double* invZd  = (double*)(st + 65536);    // 4096 f64
  float*  rowmax = (float*)(st + 98304);     // 4096
  double* imp    = (double*)(st + 114688);   // 32768 f64
  int*    cnt    = (int*)  (st + 376832);    // 32768
  int*    sel    = (int*)  (st + 507904);    // 32768
  float*  krow   = (float*)(st + 638976);    // 1024
  float*  vrow   = (float*)(st + 643072);    // 1024
  int*    usage  = (int*)  (st + 647168);    // 1
  double* vstar  = (double*)(st + 647176);   // 1 f64
  int*    bandcnt= (int*)  (st + 647184);    // 1
  int*    bandidx= (int*)  (st + 647188);    // 8192
  double* partial= (double*)(st + 680960);   // BAND_CAP*NCHUNK f64 = 512KB

  float* O   = (float*)ws;                   // [0:16M) (zeroed before PV)
  u16*   Qh  = (u16*)ws;                     // fast: [0:8M)
  u16*   MKh = (u16*)(ws + 16*MB);           // fast: [16M:80M)
  u32*   MVT = (u32*)(ws + 16*MB);           // fast: same region, after MKh dead

  float* Qhi = (float*)d_out;
  u16*   P   = (u16*)((char*)d_out + 16908544);

  dim3 blk(256);
  if (fast){
    hipMemsetAsync(st, 0, 647188 + BAND_CAP*4, stream);
    k_projq64<<<dim3(16,64),blk,0,stream>>>(hs, Wq, bq, Qhi, Qh, nullptr);
    k_cvt_mk<<<8192,blk,0,stream>>>(mk, MKh);
    k_rowproj<<<2048,blk,0,stream>>>(hs, Wk, bk, Wv, bv, krow, vrow);
    k_sweep1p<<<dim3(256,32),blk,0,stream>>>(Qh, MKh, Zrow, rmk);
    k_invz<<<16,blk,0,stream>>>(Zrow, rmk, invZ, invZd, rowmax);
    k_sweep2p<<<dim3(256,32),blk,0,stream>>>(Qh, MKh, invZ, imp, cnt, P);
    hipMemsetAsync(ws, 0, 16*MB, stream);
    k_cvt_mvt<<<16384,blk,0,stream>>>(mv, MVT);
    k_select<0><<<1,1024,0,stream>>>(imp, mage, vstar, nullptr);
    k_band<<<128,blk,0,stream>>>(imp, mage, vstar, bandcnt, bandidx);
    k_repair2<<<dim3(BAND_CAP/RB, NCHUNK),blk,0,stream>>>(bandcnt, bandidx, Qhi, mk, invZd, partial);
    k_repair_fin<<<BAND_CAP/256,blk,0,stream>>>(bandcnt, bandidx, partial, imp);
    k_pvmp<<<dim3(16,8,4),blk,0,stream>>>(P, MVT, O);
    k_projm<<<dim3(8,32),blk,0,stream>>>(O, Wo, bo, out);
    k_select<1><<<1,1024,0,stream>>>(imp, mage, nullptr, sel);
    k_scatter<<<32768,blk,0,stream>>>(mk, mv, mage, krow, vrow, sel,
        out + 4227074, out + 37781506, out + 71335938, usage);
    k_fin<<<1,blk,0,stream>>>(rowmax, cnt, usage, out + 4194304, out + 4227072);
  } else {
    hipMemsetAsync(ws, 0, 16*MB + 647188 + BAND_CAP*4, stream);
    k_projq64<<<dim3(16,64),blk,0,stream>>>(hs, Wq, bq, Qhi, nullptr, nullptr);
    k_rowproj<<<2048,blk,0,stream>>>(hs, Wk, bk, Wv, bv, krow, vrow);
    k_sweep1m<<<dim3(256,32),blk,0,stream>>>(Qhi, mk, Zrow, rmk);
    k_invz<<<16,blk,0,stream>>>(Zrow, rmk, invZ, invZd, rowmax);
    k_sweep2m<<<dim3(256,32),blk,0,stream>>>(Qhi, mk, invZ, imp, cnt, P);
    k_select<0><<<1,1024,0,stream>>>(imp, mage, vstar, nullptr);
    k_band<<<128,blk,0,stream>>>(imp, mage, vstar, bandcnt, bandidx);
    k_repair2<<<dim3(BAND_CAP/RB, NCHUNK),blk,0,stream>>>(bandcnt, bandidx, Qhi, mk, invZd, partial);
    k_repair_fin<<<BAND_CAP/256,blk,0,stream>>>(bandcnt, bandidx, partial, imp);
    k_pvm<<<dim3(32,8,4),blk,0,stream>>>(P, mv, O);
    k_projm<<<dim3(8,32),blk,0,stream>>>(O, Wo, bo, out);
    k_select<1><<<1,1024,0,stream>>>(imp, mage, nullptr, sel);
    k_scatter<<<32768,blk,0,stream>>>(mk, mv, mage, krow, vrow, sel,
        out + 4227074, out + 37781506, out + 71335938, usage);
    k_fin<<<1,blk,0,stream>>>(rowmax, cnt, usage, out + 4194304, out + 4227072);
  }
}